// Round 5
// baseline (208.569 us; speedup 1.0000x reference)
//
#include <hip/hip_runtime.h>

typedef unsigned short u16;
typedef unsigned int   u32;
typedef __attribute__((ext_vector_type(8))) short s16x8;   // 8 bf16 (4 VGPRs)
typedef __attribute__((ext_vector_type(4))) float f32x4;   // MFMA accum

#define B_   2
#define S_   2048
#define HID  1024
#define NH   16
#define N3   3072
#define M_   4096
#define C2   0.36067376022224085f   // 0.25 * log2(e)  (scale folded into log2 domain)
#define OFF2 12.0f                  // stats stabilization offset, log2 domain

__device__ __forceinline__ u16 f2b(float f) {
  union { float f; u32 u; } v; v.f = f;
  u32 r = (v.u + 0x7FFFu + ((v.u >> 16) & 1u)) >> 16;   // RNE
  return (u16)r;
}

__device__ __forceinline__ u32 cvt_pk_bf16(float lo, float hi) {
  u32 r;
  asm("v_cvt_pk_bf16_f32 %0, %1, %2" : "=v"(r) : "v"(lo), "v"(hi));
  return r;
}

// async global->LDS, 16B per lane, wave-uniform LDS base (m97 pattern, GEMM only)
#define GLL(gp, lp)                                                          \
  __builtin_amdgcn_global_load_lds(                                          \
      (const __attribute__((address_space(1))) void*)(gp),                   \
      (__attribute__((address_space(3))) void*)(lp), 16, 0, 0)

// ---------------------------------------------------------------------------
// fp32 -> bf16 elementwise (x)
// ---------------------------------------------------------------------------
__global__ __launch_bounds__(256) void conv_bf16(const float* __restrict__ in,
                                                 u16* __restrict__ out, int n4) {
  int i = blockIdx.x * 256 + threadIdx.x;
  if (i >= n4) return;
  float4 v = ((const float4*)in)[i];
  ushort4 o = { f2b(v.x), f2b(v.y), f2b(v.z), f2b(v.w) };
  ((ushort4*)out)[i] = o;
}

// ---------------------------------------------------------------------------
// fp32 [K][N] -> bf16 [N][K] transpose (weights)
// ---------------------------------------------------------------------------
__global__ __launch_bounds__(256) void transpose_bf16(const float* __restrict__ in,
                                                      u16* __restrict__ out,
                                                      int K, int N) {
  __shared__ float T[32][33];
  const int t = threadIdx.x;
  const int k0 = blockIdx.y * 32, n0 = blockIdx.x * 32;
  {
    int r = t >> 3, c4 = (t & 7) * 4;
    float4 v = *(const float4*)(in + (size_t)(k0 + r) * N + n0 + c4);
    T[r][c4 + 0] = v.x; T[r][c4 + 1] = v.y; T[r][c4 + 2] = v.z; T[r][c4 + 3] = v.w;
  }
  __syncthreads();
  int n = t >> 3, kc = (t & 7) * 4;
  ushort4 o = { f2b(T[kc + 0][n]), f2b(T[kc + 1][n]), f2b(T[kc + 2][n]), f2b(T[kc + 3][n]) };
  *(ushort4*)(out + (size_t)(n0 + n) * K + k0 + kc) = o;
}

// ---------------------------------------------------------------------------
// bf16 kqv V-part -> Vt[bh][d=64][s=2048]  (LDS transpose, pitch 66)
// ---------------------------------------------------------------------------
__global__ __launch_bounds__(256) void v_transpose(const u16* __restrict__ kqv,
                                                   u16* __restrict__ Vtg) {
  __shared__ u16 Vl[64 * 66];
  const int t = threadIdx.x;
  const int bh = blockIdx.y, b = bh >> 4, h = bh & 15;
  const int s0 = blockIdx.x * 64;
  const u16* src = kqv + (size_t)b * S_ * N3 + 2 * HID + h * 64;
  #pragma unroll
  for (int cc = 0; cc < 2; ++cc) {
    int c = t + cc * 256;
    int row = c >> 3, dc = c & 7;
    uint4 v = *(const uint4*)(src + (size_t)(s0 + row) * N3 + dc * 8);
    u32* pe = (u32*)&v;
    #pragma unroll
    for (int e = 0; e < 4; ++e)
      *(u32*)(Vl + row * 66 + dc * 8 + 2 * e) = pe[e];
  }
  __syncthreads();
  #pragma unroll
  for (int cc = 0; cc < 2; ++cc) {
    int c = t + cc * 256;
    int d = c >> 3, sc = c & 7;
    u16 tmp[8];
    #pragma unroll
    for (int j = 0; j < 8; ++j) tmp[j] = Vl[(sc * 8 + j) * 66 + d];
    *(uint4*)(Vtg + ((size_t)bh * 64 + d) * S_ + s0 + sc * 8) = *(uint4*)tmp;
  }
}

// ---------------------------------------------------------------------------
// bf16 MFMA GEMM (m97 structure): C[M,N] = A[M,K] @ Bt[N,K]^T + bias
// 128x128 tile, BK=32, linear LDS [128][32], global_load_lds width 16.
// ---------------------------------------------------------------------------
template <int OUTBF16>
__global__ __launch_bounds__(256) void gemm_bf16(const u16* __restrict__ A,
                                                 const u16* __restrict__ Bt,
                                                 const float* __restrict__ bias,
                                                 void* __restrict__ Cout,
                                                 int M, int N, int K) {
  __shared__ u16 Al[128 * 32];
  __shared__ u16 Bl[128 * 32];
  const int t = threadIdx.x, lane = t & 63, w = t >> 6;
  const int m0 = blockIdx.y * 128, n0 = blockIdx.x * 128;
  const int wm = (w >> 1) * 64, wn = (w & 1) * 64;
  const int r = lane & 15, g = lane >> 4;

  f32x4 acc[4][4];
  #pragma unroll
  for (int i = 0; i < 4; ++i)
    #pragma unroll
    for (int j = 0; j < 4; ++j) acc[i][j] = (f32x4){0.f, 0.f, 0.f, 0.f};

  const int c0 = (w << 7) + lane, c1 = c0 + 64;
  const int ar0 = c0 >> 2, ak0 = (c0 & 3) << 3;
  const int ar1 = c1 >> 2, ak1 = (c1 & 3) << 3;

  for (int k0 = 0; k0 < K; k0 += 32) {
    __syncthreads();
    GLL(A  + (size_t)(m0 + ar0) * K + k0 + ak0, Al + (w << 10));
    GLL(A  + (size_t)(m0 + ar1) * K + k0 + ak1, Al + (w << 10) + 512);
    GLL(Bt + (size_t)(n0 + ar0) * K + k0 + ak0, Bl + (w << 10));
    GLL(Bt + (size_t)(n0 + ar1) * K + k0 + ak1, Bl + (w << 10) + 512);
    __syncthreads();

    s16x8 af[4], bf[4];
    #pragma unroll
    for (int mf = 0; mf < 4; ++mf)
      af[mf] = *(const s16x8*)(Al + (wm + mf * 16 + r) * 32 + g * 8);
    #pragma unroll
    for (int nf = 0; nf < 4; ++nf)
      bf[nf] = *(const s16x8*)(Bl + (wn + nf * 16 + r) * 32 + g * 8);
    #pragma unroll
    for (int mf = 0; mf < 4; ++mf)
      #pragma unroll
      for (int nf = 0; nf < 4; ++nf)
        acc[mf][nf] = __builtin_amdgcn_mfma_f32_16x16x32_bf16(af[mf], bf[nf], acc[mf][nf], 0, 0, 0);
  }

  float bv[4];
  #pragma unroll
  for (int nf = 0; nf < 4; ++nf) bv[nf] = bias[n0 + wn + nf * 16 + r];

  #pragma unroll
  for (int mf = 0; mf < 4; ++mf)
    #pragma unroll
    for (int nf = 0; nf < 4; ++nf)
      #pragma unroll
      for (int q = 0; q < 4; ++q) {
        float o = acc[mf][nf][q] + bv[nf];
        size_t idx = (size_t)(m0 + wm + mf * 16 + 4 * g + q) * N + (n0 + wn + nf * 16 + r);
        if (OUTBF16) ((u16*)Cout)[idx] = f2b(o);
        else         ((float*)Cout)[idx] = o;
      }
}

// ---------------------------------------------------------------------------
// Stats: L2[s] = OFF2 + log2( sum_n exp2(C2*K_s.Q_n - OFF2) )
// Round-2-proven staging (explicit uint4 -> LDS, pitch 72).
// ---------------------------------------------------------------------------
__global__ __launch_bounds__(256) void attn_stats(const u16* __restrict__ kqv,
                                                  float* __restrict__ L2) {
  __shared__ u16 Kl[64 * 72];
  __shared__ u16 Ql[64 * 72];
  const int t = threadIdx.x, lane = t & 63, w = t >> 6;
  const int bh = blockIdx.y, b = bh >> 4, h = bh & 15;
  const int s0 = blockIdx.x * 64;
  const u16* base = kqv + (size_t)b * S_ * N3;
  const int r = lane & 15, g = lane >> 4;

  {  // stage K tile [64 s][64 d] once (visible after first in-loop barrier pair)
    int c = t;       int row = c >> 3, dc = c & 7;
    *(uint4*)(Kl + row * 72 + dc * 8) =
        *(const uint4*)(base + (size_t)(s0 + row) * N3 + h * 64 + dc * 8);
    c = t + 256;     row = c >> 3; dc = c & 7;
    *(uint4*)(Kl + row * 72 + dc * 8) =
        *(const uint4*)(base + (size_t)(s0 + row) * N3 + h * 64 + dc * 8);
  }

  float z[4] = {0.f, 0.f, 0.f, 0.f};

  for (int nt = 0; nt < 32; ++nt) {
    const int n0 = nt * 64;
    __syncthreads();   // prev Q reads done
    {
      int c = t;       int row = c >> 3, dc = c & 7;
      *(uint4*)(Ql + row * 72 + dc * 8) =
          *(const uint4*)(base + (size_t)(n0 + row) * N3 + HID + h * 64 + dc * 8);
      c = t + 256;     row = c >> 3; dc = c & 7;
      *(uint4*)(Ql + row * 72 + dc * 8) =
          *(const uint4*)(base + (size_t)(n0 + row) * N3 + HID + h * 64 + dc * 8);
    }
    __syncthreads();

    s16x8 ka0 = *(const s16x8*)(Kl + (w * 16 + r) * 72 + g * 8);
    s16x8 ka1 = *(const s16x8*)(Kl + (w * 16 + r) * 72 + 32 + g * 8);
    #pragma unroll
    for (int nf = 0; nf < 4; ++nf) {
      f32x4 sc = (f32x4){0.f, 0.f, 0.f, 0.f};
      s16x8 qb0 = *(const s16x8*)(Ql + (nf * 16 + r) * 72 + g * 8);
      s16x8 qb1 = *(const s16x8*)(Ql + (nf * 16 + r) * 72 + 32 + g * 8);
      sc = __builtin_amdgcn_mfma_f32_16x16x32_bf16(ka0, qb0, sc, 0, 0, 0);
      sc = __builtin_amdgcn_mfma_f32_16x16x32_bf16(ka1, qb1, sc, 0, 0, 0);
      #pragma unroll
      for (int q = 0; q < 4; ++q)
        z[q] += exp2f(fmaf(sc[q], C2, -OFF2));
    }
  }
  #pragma unroll
  for (int m = 1; m <= 8; m <<= 1)
    #pragma unroll
    for (int q = 0; q < 4; ++q) z[q] += __shfl_xor(z[q], m);
  if (r == 0)
    #pragma unroll
    for (int q = 0; q < 4; ++q)
      L2[(size_t)bh * S_ + s0 + w * 16 + 4 * g + q] = OFF2 + log2f(z[q]);
}

// ---------------------------------------------------------------------------
// PV pass: out[n,d] = sum_s exp2(C2*Q_n.K_s - L2[s]) * V[s,d]
// Round-2-proven layouts (pitch 72, separate P buffer); V pre-transposed.
// ---------------------------------------------------------------------------
__global__ __launch_bounds__(256) void attn_pv(const u16* __restrict__ kqv,
                                               const u16* __restrict__ Vtg,
                                               const float* __restrict__ L2,
                                               u16* __restrict__ attn) {
  __shared__ u16 Ql[64 * 72];
  __shared__ u16 Kl[64 * 72];
  __shared__ u16 Vl[64 * 72];
  __shared__ u16 Pl[64 * 72];
  const int t = threadIdx.x, lane = t & 63, w = t >> 6;
  const int bh = blockIdx.y, b = bh >> 4, h = bh & 15;
  const int n0 = blockIdx.x * 64;
  const u16* base = kqv + (size_t)b * S_ * N3;
  const u16* vtb  = Vtg + (size_t)bh * 64 * S_;
  const float* Lb = L2 + (size_t)bh * S_;
  const int r = lane & 15, g = lane >> 4;

  {  // stage Q tile [64 n][64 d] once
    int c = t;       int row = c >> 3, dc = c & 7;
    *(uint4*)(Ql + row * 72 + dc * 8) =
        *(const uint4*)(base + (size_t)(n0 + row) * N3 + HID + h * 64 + dc * 8);
    c = t + 256;     row = c >> 3; dc = c & 7;
    *(uint4*)(Ql + row * 72 + dc * 8) =
        *(const uint4*)(base + (size_t)(n0 + row) * N3 + HID + h * 64 + dc * 8);
  }
  __syncthreads();
  const s16x8 qa0 = *(const s16x8*)(Ql + (w * 16 + r) * 72 + g * 8);
  const s16x8 qa1 = *(const s16x8*)(Ql + (w * 16 + r) * 72 + 32 + g * 8);

  f32x4 oacc[4];
  #pragma unroll
  for (int i = 0; i < 4; ++i) oacc[i] = (f32x4){0.f, 0.f, 0.f, 0.f};

  for (int st = 0; st < 32; ++st) {
    const int s0 = st * 64;
    float Lv[4];
    #pragma unroll
    for (int sf = 0; sf < 4; ++sf) Lv[sf] = Lb[s0 + sf * 16 + r];

    __syncthreads();   // prev chunk's K/V/P reads done
    {  // stage K [64 s][64 d]
      int c = t;       int row = c >> 3, dc = c & 7;
      *(uint4*)(Kl + row * 72 + dc * 8) =
          *(const uint4*)(base + (size_t)(s0 + row) * N3 + h * 64 + dc * 8);
      c = t + 256;     row = c >> 3; dc = c & 7;
      *(uint4*)(Kl + row * 72 + dc * 8) =
          *(const uint4*)(base + (size_t)(s0 + row) * N3 + h * 64 + dc * 8);
    }
    {  // stage Vt [64 d][64 s] (pre-transposed in global)
      int c = t;       int row = c >> 3, dc = c & 7;
      *(uint4*)(Vl + row * 72 + dc * 8) =
          *(const uint4*)(vtb + (size_t)row * S_ + s0 + dc * 8);
      c = t + 256;     row = c >> 3; dc = c & 7;
      *(uint4*)(Vl + row * 72 + dc * 8) =
          *(const uint4*)(vtb + (size_t)row * S_ + s0 + dc * 8);
    }
    __syncthreads();

    // scoreT[n][s], weight = exp2(C2*sc - L2[s]) -> Pl (round-2 layout)
    #pragma unroll
    for (int sf = 0; sf < 4; ++sf) {
      f32x4 sc = (f32x4){0.f, 0.f, 0.f, 0.f};
      s16x8 kb0 = *(const s16x8*)(Kl + (sf * 16 + r) * 72 + g * 8);
      s16x8 kb1 = *(const s16x8*)(Kl + (sf * 16 + r) * 72 + 32 + g * 8);
      sc = __builtin_amdgcn_mfma_f32_16x16x32_bf16(qa0, kb0, sc, 0, 0, 0);
      sc = __builtin_amdgcn_mfma_f32_16x16x32_bf16(qa1, kb1, sc, 0, 0, 0);
      float p0 = exp2f(fmaf(sc[0], C2, -Lv[sf]));
      float p1 = exp2f(fmaf(sc[1], C2, -Lv[sf]));
      float p2 = exp2f(fmaf(sc[2], C2, -Lv[sf]));
      float p3 = exp2f(fmaf(sc[3], C2, -Lv[sf]));
      u32 pk01 = cvt_pk_bf16(p0, p1);
      u32 pk23 = cvt_pk_bf16(p2, p3);
      int pbase = (w * 16 + 4 * g) * 72 + sf * 16 + r;
      Pl[pbase]           = (u16)pk01;           // row n = w*16+4g+0
      Pl[pbase + 72]      = (u16)(pk01 >> 16);   // +1
      Pl[pbase + 144]     = (u16)pk23;           // +2
      Pl[pbase + 216]     = (u16)(pk23 >> 16);   // +3
    }
    // PV: P rows are wave-private; same-wave lgkm ordering suffices
    #pragma unroll
    for (int ks = 0; ks < 2; ++ks) {
      s16x8 pa = *(const s16x8*)(Pl + (w * 16 + r) * 72 + ks * 32 + g * 8);
      #pragma unroll
      for (int df = 0; df < 4; ++df) {
        s16x8 vb = *(const s16x8*)(Vl + (df * 16 + r) * 72 + ks * 32 + g * 8);
        oacc[df] = __builtin_amdgcn_mfma_f32_16x16x32_bf16(pa, vb, oacc[df], 0, 0, 0);
      }
    }
  }

  #pragma unroll
  for (int df = 0; df < 4; ++df)
    #pragma unroll
    for (int q = 0; q < 4; ++q)
      attn[(size_t)(b * S_ + n0 + w * 16 + 4 * g + q) * HID + h * 64 + df * 16 + r] =
          f2b(oacc[df][q]);
}

// ---------------------------------------------------------------------------
extern "C" void kernel_launch(void* const* d_in, const int* in_sizes, int n_in,
                              void* d_out, int out_size, void* d_ws, size_t ws_size,
                              hipStream_t stream) {
  const float* x     = (const float*)d_in[0];
  const float* kqv_w = (const float*)d_in[1];
  const float* kqv_b = (const float*)d_in[2];
  const float* ff_w  = (const float*)d_in[3];
  const float* ff_b  = (const float*)d_in[4];
  float* out = (float*)d_out;

  u16* xb    = (u16*)d_ws;                         // 4096*1024
  u16* w1t   = xb   + (size_t)M_ * HID;            // 3072*1024
  u16* w2t   = w1t  + (size_t)N3 * HID;            // 1024*1024
  u16* kqvb  = w2t  + (size_t)HID * HID;           // 4096*3072
  u16* vtg   = kqvb + (size_t)M_ * N3;             // 32*64*2048
  float* Lr  = (float*)(vtg + (size_t)B_ * NH * 64 * S_);   // 32*2048 f32
  u16* attnb = (u16*)(Lr + (size_t)B_ * NH * S_);  // 4096*1024
  // total ~56.3 MB

  dim3 blk(256);
  conv_bf16<<<dim3((M_ * HID / 4 + 255) / 256), blk, 0, stream>>>(x, xb, M_ * HID / 4);
  transpose_bf16<<<dim3(N3 / 32, HID / 32), blk, 0, stream>>>(kqv_w, w1t, HID, N3);
  transpose_bf16<<<dim3(HID / 32, HID / 32), blk, 0, stream>>>(ff_w, w2t, HID, HID);

  gemm_bf16<1><<<dim3(N3 / 128, M_ / 128), blk, 0, stream>>>(
      xb, w1t, kqv_b, kqvb, M_, N3, HID);

  v_transpose<<<dim3(S_ / 64, B_ * NH), blk, 0, stream>>>(kqvb, vtg);
  attn_stats <<<dim3(S_ / 64, B_ * NH), blk, 0, stream>>>(kqvb, Lr);
  attn_pv    <<<dim3(S_ / 64, B_ * NH), blk, 0, stream>>>(kqvb, vtg, Lr, attnb);

  gemm_bf16<0><<<dim3(HID / 128, M_ / 128), blk, 0, stream>>>(
      attnb, w2t, ff_b, out, M_, HID, HID);
}

// Round 6
// 206.141 us; speedup vs baseline: 1.0118x; 1.0118x over previous
//
#include <hip/hip_runtime.h>

typedef unsigned short u16;
typedef unsigned int   u32;
typedef __attribute__((ext_vector_type(8))) short s16x8;   // 8 bf16 (4 VGPRs)
typedef __attribute__((ext_vector_type(4))) float f32x4;   // MFMA accum

#define B_   2
#define S_   2048
#define HID  1024
#define NH   16
#define N3   3072
#define M_   4096
#define C2   0.36067376022224085f   // 0.25 * log2(e)  (scale folded into log2 domain)
#define OFF2 12.0f                  // stats stabilization offset, log2 domain

__device__ __forceinline__ u16 f2b(float f) {
  union { float f; u32 u; } v; v.f = f;
  u32 r = (v.u + 0x7FFFu + ((v.u >> 16) & 1u)) >> 16;   // RNE
  return (u16)r;
}

__device__ __forceinline__ u32 cvt_pk_bf16(float lo, float hi) {
  u32 r;
  asm("v_cvt_pk_bf16_f32 %0, %1, %2" : "=v"(r) : "v"(lo), "v"(hi));
  return r;
}

// async global->LDS, 16B per lane, wave-uniform LDS base (m97 pattern, GEMM only)
#define GLL(gp, lp)                                                          \
  __builtin_amdgcn_global_load_lds(                                          \
      (const __attribute__((address_space(1))) void*)(gp),                   \
      (__attribute__((address_space(3))) void*)(lp), 16, 0, 0)

// ---------------------------------------------------------------------------
// fp32 -> bf16 elementwise (x)
// ---------------------------------------------------------------------------
__global__ __launch_bounds__(256) void conv_bf16(const float* __restrict__ in,
                                                 u16* __restrict__ out, int n4) {
  int i = blockIdx.x * 256 + threadIdx.x;
  if (i >= n4) return;
  float4 v = ((const float4*)in)[i];
  ushort4 o = { f2b(v.x), f2b(v.y), f2b(v.z), f2b(v.w) };
  ((ushort4*)out)[i] = o;
}

// ---------------------------------------------------------------------------
// fp32 [K][N] -> bf16 [N][K] transpose (weights)
// ---------------------------------------------------------------------------
__global__ __launch_bounds__(256) void transpose_bf16(const float* __restrict__ in,
                                                      u16* __restrict__ out,
                                                      int K, int N) {
  __shared__ float T[32][33];
  const int t = threadIdx.x;
  const int k0 = blockIdx.y * 32, n0 = blockIdx.x * 32;
  {
    int r = t >> 3, c4 = (t & 7) * 4;
    float4 v = *(const float4*)(in + (size_t)(k0 + r) * N + n0 + c4);
    T[r][c4 + 0] = v.x; T[r][c4 + 1] = v.y; T[r][c4 + 2] = v.z; T[r][c4 + 3] = v.w;
  }
  __syncthreads();
  int n = t >> 3, kc = (t & 7) * 4;
  ushort4 o = { f2b(T[kc + 0][n]), f2b(T[kc + 1][n]), f2b(T[kc + 2][n]), f2b(T[kc + 3][n]) };
  *(ushort4*)(out + (size_t)(n0 + n) * K + k0 + kc) = o;
}

// ---------------------------------------------------------------------------
// bf16 kqv V-part -> Vt[bh][d=64][s=2048]  (LDS transpose, pitch 66)
// ---------------------------------------------------------------------------
__global__ __launch_bounds__(256) void v_transpose(const u16* __restrict__ kqv,
                                                   u16* __restrict__ Vtg) {
  __shared__ u16 Vl[64 * 66];
  const int t = threadIdx.x;
  const int bh = blockIdx.y, b = bh >> 4, h = bh & 15;
  const int s0 = blockIdx.x * 64;
  const u16* src = kqv + (size_t)b * S_ * N3 + 2 * HID + h * 64;
  #pragma unroll
  for (int cc = 0; cc < 2; ++cc) {
    int c = t + cc * 256;
    int row = c >> 3, dc = c & 7;
    uint4 v = *(const uint4*)(src + (size_t)(s0 + row) * N3 + dc * 8);
    u32* pe = (u32*)&v;
    #pragma unroll
    for (int e = 0; e < 4; ++e)
      *(u32*)(Vl + row * 66 + dc * 8 + 2 * e) = pe[e];
  }
  __syncthreads();
  #pragma unroll
  for (int cc = 0; cc < 2; ++cc) {
    int c = t + cc * 256;
    int d = c >> 3, sc = c & 7;
    u16 tmp[8];
    #pragma unroll
    for (int j = 0; j < 8; ++j) tmp[j] = Vl[(sc * 8 + j) * 66 + d];
    *(uint4*)(Vtg + ((size_t)bh * 64 + d) * S_ + s0 + sc * 8) = *(uint4*)tmp;
  }
}

// ---------------------------------------------------------------------------
// bf16 MFMA GEMM (m97 structure): C[M,N] = A[M,K] @ Bt[N,K]^T + bias
// 128x128 tile, BK=32, linear LDS [128][32], global_load_lds width 16.
// ---------------------------------------------------------------------------
template <int OUTBF16>
__global__ __launch_bounds__(256) void gemm_bf16(const u16* __restrict__ A,
                                                 const u16* __restrict__ Bt,
                                                 const float* __restrict__ bias,
                                                 void* __restrict__ Cout,
                                                 int M, int N, int K) {
  __shared__ u16 Al[128 * 32];
  __shared__ u16 Bl[128 * 32];
  const int t = threadIdx.x, lane = t & 63, w = t >> 6;
  const int m0 = blockIdx.y * 128, n0 = blockIdx.x * 128;
  const int wm = (w >> 1) * 64, wn = (w & 1) * 64;
  const int r = lane & 15, g = lane >> 4;

  f32x4 acc[4][4];
  #pragma unroll
  for (int i = 0; i < 4; ++i)
    #pragma unroll
    for (int j = 0; j < 4; ++j) acc[i][j] = (f32x4){0.f, 0.f, 0.f, 0.f};

  const int c0 = (w << 7) + lane, c1 = c0 + 64;
  const int ar0 = c0 >> 2, ak0 = (c0 & 3) << 3;
  const int ar1 = c1 >> 2, ak1 = (c1 & 3) << 3;

  for (int k0 = 0; k0 < K; k0 += 32) {
    __syncthreads();
    GLL(A  + (size_t)(m0 + ar0) * K + k0 + ak0, Al + (w << 10));
    GLL(A  + (size_t)(m0 + ar1) * K + k0 + ak1, Al + (w << 10) + 512);
    GLL(Bt + (size_t)(n0 + ar0) * K + k0 + ak0, Bl + (w << 10));
    GLL(Bt + (size_t)(n0 + ar1) * K + k0 + ak1, Bl + (w << 10) + 512);
    __syncthreads();

    s16x8 af[4], bf[4];
    #pragma unroll
    for (int mf = 0; mf < 4; ++mf)
      af[mf] = *(const s16x8*)(Al + (wm + mf * 16 + r) * 32 + g * 8);
    #pragma unroll
    for (int nf = 0; nf < 4; ++nf)
      bf[nf] = *(const s16x8*)(Bl + (wn + nf * 16 + r) * 32 + g * 8);
    #pragma unroll
    for (int mf = 0; mf < 4; ++mf)
      #pragma unroll
      for (int nf = 0; nf < 4; ++nf)
        acc[mf][nf] = __builtin_amdgcn_mfma_f32_16x16x32_bf16(af[mf], bf[nf], acc[mf][nf], 0, 0, 0);
  }

  float bv[4];
  #pragma unroll
  for (int nf = 0; nf < 4; ++nf) bv[nf] = bias[n0 + wn + nf * 16 + r];

  #pragma unroll
  for (int mf = 0; mf < 4; ++mf)
    #pragma unroll
    for (int nf = 0; nf < 4; ++nf)
      #pragma unroll
      for (int q = 0; q < 4; ++q) {
        float o = acc[mf][nf][q] + bv[nf];
        size_t idx = (size_t)(m0 + wm + mf * 16 + 4 * g + q) * N + (n0 + wn + nf * 16 + r);
        if (OUTBF16) ((u16*)Cout)[idx] = f2b(o);
        else         ((float*)Cout)[idx] = o;
      }
}

// ---------------------------------------------------------------------------
// Stats: L2[s] = OFF2 + log2( sum_n exp2(C2*K_s.Q_n - OFF2) )
// s-tile 128 (each wave owns 32 s-rows); K staged once, frags hoisted.
// ---------------------------------------------------------------------------
__global__ __launch_bounds__(256, 4) void attn_stats(const u16* __restrict__ kqv,
                                                     float* __restrict__ L2) {
  __shared__ u16 Kl[128 * 72];
  __shared__ u16 Ql[64 * 72];
  const int t = threadIdx.x, lane = t & 63, w = t >> 6;
  const int bh = blockIdx.y, b = bh >> 4, h = bh & 15;
  const int s0 = blockIdx.x * 128;
  const u16* base = kqv + (size_t)b * S_ * N3;
  const int r = lane & 15, g = lane >> 4;

  #pragma unroll
  for (int cc = 0; cc < 4; ++cc) {
    int c = t + cc * 256;
    int row = c >> 3, dc = c & 7;
    *(uint4*)(Kl + row * 72 + dc * 8) =
        *(const uint4*)(base + (size_t)(s0 + row) * N3 + h * 64 + dc * 8);
  }
  __syncthreads();
  s16x8 ka[2][2];
  #pragma unroll
  for (int sf2 = 0; sf2 < 2; ++sf2) {
    ka[sf2][0] = *(const s16x8*)(Kl + (w * 32 + sf2 * 16 + r) * 72 + g * 8);
    ka[sf2][1] = *(const s16x8*)(Kl + (w * 32 + sf2 * 16 + r) * 72 + 32 + g * 8);
  }

  float z[2][4] = {};

  for (int nt = 0; nt < 32; ++nt) {
    const int n0 = nt * 64;
    __syncthreads();   // prev Q reads done
    #pragma unroll
    for (int cc = 0; cc < 2; ++cc) {
      int c = t + cc * 256;
      int row = c >> 3, dc = c & 7;
      *(uint4*)(Ql + row * 72 + dc * 8) =
          *(const uint4*)(base + (size_t)(n0 + row) * N3 + HID + h * 64 + dc * 8);
    }
    __syncthreads();

    #pragma unroll
    for (int nf = 0; nf < 4; ++nf) {
      s16x8 qb0 = *(const s16x8*)(Ql + (nf * 16 + r) * 72 + g * 8);
      s16x8 qb1 = *(const s16x8*)(Ql + (nf * 16 + r) * 72 + 32 + g * 8);
      #pragma unroll
      for (int sf2 = 0; sf2 < 2; ++sf2) {
        f32x4 sc = (f32x4){0.f, 0.f, 0.f, 0.f};
        sc = __builtin_amdgcn_mfma_f32_16x16x32_bf16(ka[sf2][0], qb0, sc, 0, 0, 0);
        sc = __builtin_amdgcn_mfma_f32_16x16x32_bf16(ka[sf2][1], qb1, sc, 0, 0, 0);
        #pragma unroll
        for (int q = 0; q < 4; ++q)
          z[sf2][q] += exp2f(fmaf(sc[q], C2, -OFF2));
      }
    }
  }
  #pragma unroll
  for (int m = 1; m <= 8; m <<= 1)
    #pragma unroll
    for (int sf2 = 0; sf2 < 2; ++sf2)
      #pragma unroll
      for (int q = 0; q < 4; ++q) z[sf2][q] += __shfl_xor(z[sf2][q], m);
  if (r == 0)
    #pragma unroll
    for (int sf2 = 0; sf2 < 2; ++sf2)
      #pragma unroll
      for (int q = 0; q < 4; ++q)
        L2[(size_t)bh * S_ + s0 + w * 32 + sf2 * 16 + 4 * g + q] =
            OFF2 + log2f(z[sf2][q]);
}

// ---------------------------------------------------------------------------
// PV pass: out[n,d] = sum_s exp2(C2*Q_n.K_s - L2[s]) * V[s,d]
// n-tile 128 (each wave owns 32 n-rows). P aliases Q buffer (wave w reads
// exactly rows [32w,32w+32) of Q into regs, then overwrites only those rows).
// P bank swizzle: col' = ((s>>3) ^ 2*((n>>2)&3))*8 + (s&7)  [XOR-bijective;
// write and read reduce to the same col' -- verified symbolically].
// ---------------------------------------------------------------------------
__global__ __launch_bounds__(256, 4) void attn_pv(const u16* __restrict__ kqv,
                                                  const u16* __restrict__ Vtg,
                                                  const float* __restrict__ L2,
                                                  u16* __restrict__ attn) {
  __shared__ u16 QPl[128 * 72];   // Q tile, then P tile
  __shared__ u16 Kl[64 * 72];
  __shared__ u16 Vl[64 * 72];
  const int t = threadIdx.x, lane = t & 63, w = t >> 6;
  const int bh = blockIdx.y, b = bh >> 4, h = bh & 15;
  const int n0 = blockIdx.x * 128;
  const u16* base = kqv + (size_t)b * S_ * N3;
  const u16* vtb  = Vtg + (size_t)bh * 64 * S_;
  const float* Lb = L2 + (size_t)bh * S_;
  const int r = lane & 15, g = lane >> 4;

  #pragma unroll
  for (int cc = 0; cc < 4; ++cc) {
    int c = t + cc * 256;
    int row = c >> 3, dc = c & 7;
    *(uint4*)(QPl + row * 72 + dc * 8) =
        *(const uint4*)(base + (size_t)(n0 + row) * N3 + HID + h * 64 + dc * 8);
  }
  __syncthreads();
  s16x8 qa[2][2];
  #pragma unroll
  for (int nf2 = 0; nf2 < 2; ++nf2) {
    qa[nf2][0] = *(const s16x8*)(QPl + (w * 32 + nf2 * 16 + r) * 72 + g * 8);
    qa[nf2][1] = *(const s16x8*)(QPl + (w * 32 + nf2 * 16 + r) * 72 + 32 + g * 8);
  }

  f32x4 oacc[2][4];
  #pragma unroll
  for (int i = 0; i < 2; ++i)
    #pragma unroll
    for (int j = 0; j < 4; ++j) oacc[i][j] = (f32x4){0.f, 0.f, 0.f, 0.f};

  for (int st = 0; st < 32; ++st) {
    const int s0 = st * 64;
    float Lv[4];
    #pragma unroll
    for (int sf = 0; sf < 4; ++sf) Lv[sf] = Lb[s0 + sf * 16 + r];

    __syncthreads();   // prev chunk's K/V/P reads done (iter0: Q frag reads done)
    #pragma unroll
    for (int cc = 0; cc < 2; ++cc) {
      int c = t + cc * 256;
      int row = c >> 3, dc = c & 7;
      *(uint4*)(Kl + row * 72 + dc * 8) =
          *(const uint4*)(base + (size_t)(s0 + row) * N3 + h * 64 + dc * 8);
      *(uint4*)(Vl + row * 72 + dc * 8) =
          *(const uint4*)(vtb + (size_t)row * S_ + s0 + dc * 8);
    }
    __syncthreads();

    // scoreT[n][s] -> weights -> P (swizzled, bank-separated per g)
    #pragma unroll
    for (int nf2 = 0; nf2 < 2; ++nf2)
      #pragma unroll
      for (int sf = 0; sf < 4; ++sf) {
        f32x4 sc = (f32x4){0.f, 0.f, 0.f, 0.f};
        s16x8 kb0 = *(const s16x8*)(Kl + (sf * 16 + r) * 72 + g * 8);
        s16x8 kb1 = *(const s16x8*)(Kl + (sf * 16 + r) * 72 + 32 + g * 8);
        sc = __builtin_amdgcn_mfma_f32_16x16x32_bf16(qa[nf2][0], kb0, sc, 0, 0, 0);
        sc = __builtin_amdgcn_mfma_f32_16x16x32_bf16(qa[nf2][1], kb1, sc, 0, 0, 0);
        float p0 = exp2f(fmaf(sc[0], C2, -Lv[sf]));
        float p1 = exp2f(fmaf(sc[1], C2, -Lv[sf]));
        float p2 = exp2f(fmaf(sc[2], C2, -Lv[sf]));
        float p3 = exp2f(fmaf(sc[3], C2, -Lv[sf]));
        u32 pk01 = cvt_pk_bf16(p0, p1);
        u32 pk23 = cvt_pk_bf16(p2, p3);
        int pc = (sf * 2 + (r >> 3)) ^ (2 * g);
        int pbase = (w * 32 + nf2 * 16 + 4 * g) * 72 + pc * 8 + (r & 7);
        QPl[pbase]       = (u16)pk01;           // row +0
        QPl[pbase + 72]  = (u16)(pk01 >> 16);   // row +1
        QPl[pbase + 144] = (u16)pk23;           // row +2
        QPl[pbase + 216] = (u16)(pk23 >> 16);   // row +3
      }
    // PV: P rows are wave-private; same-wave lgkm ordering suffices
    #pragma unroll
    for (int nf2 = 0; nf2 < 2; ++nf2)
      #pragma unroll
      for (int ks = 0; ks < 2; ++ks) {
        s16x8 pa = *(const s16x8*)(QPl + (w * 32 + nf2 * 16 + r) * 72 +
                                   ((ks * 4 + g) ^ (2 * (r >> 2))) * 8);
        #pragma unroll
        for (int df = 0; df < 4; ++df) {
          s16x8 vb = *(const s16x8*)(Vl + (df * 16 + r) * 72 + ks * 32 + g * 8);
          oacc[nf2][df] = __builtin_amdgcn_mfma_f32_16x16x32_bf16(pa, vb, oacc[nf2][df], 0, 0, 0);
        }
      }
  }

  #pragma unroll
  for (int nf2 = 0; nf2 < 2; ++nf2)
    #pragma unroll
    for (int df = 0; df < 4; ++df)
      #pragma unroll
      for (int q = 0; q < 4; ++q)
        attn[(size_t)(b * S_ + n0 + w * 32 + nf2 * 16 + 4 * g + q) * HID +
             h * 64 + df * 16 + r] = f2b(oacc[nf2][df][q]);
}

// ---------------------------------------------------------------------------
extern "C" void kernel_launch(void* const* d_in, const int* in_sizes, int n_in,
                              void* d_out, int out_size, void* d_ws, size_t ws_size,
                              hipStream_t stream) {
  const float* x     = (const float*)d_in[0];
  const float* kqv_w = (const float*)d_in[1];
  const float* kqv_b = (const float*)d_in[2];
  const float* ff_w  = (const float*)d_in[3];
  const float* ff_b  = (const float*)d_in[4];
  float* out = (float*)d_out;

  u16* xb    = (u16*)d_ws;                         // 4096*1024
  u16* w1t   = xb   + (size_t)M_ * HID;            // 3072*1024
  u16* w2t   = w1t  + (size_t)N3 * HID;            // 1024*1024
  u16* kqvb  = w2t  + (size_t)HID * HID;           // 4096*3072
  u16* vtg   = kqvb + (size_t)M_ * N3;             // 32*64*2048
  float* Lr  = (float*)(vtg + (size_t)B_ * NH * 64 * S_);   // 32*2048 f32
  u16* attnb = (u16*)(Lr + (size_t)B_ * NH * S_);  // 4096*1024
  // total ~56.3 MB

  dim3 blk(256);
  conv_bf16<<<dim3((M_ * HID / 4 + 255) / 256), blk, 0, stream>>>(x, xb, M_ * HID / 4);
  transpose_bf16<<<dim3(N3 / 32, HID / 32), blk, 0, stream>>>(kqv_w, w1t, HID, N3);
  transpose_bf16<<<dim3(HID / 32, HID / 32), blk, 0, stream>>>(ff_w, w2t, HID, HID);

  gemm_bf16<1><<<dim3(N3 / 128, M_ / 128), blk, 0, stream>>>(
      xb, w1t, kqv_b, kqvb, M_, N3, HID);

  v_transpose<<<dim3(S_ / 64, B_ * NH), blk, 0, stream>>>(kqvb, vtg);
  attn_stats <<<dim3(S_ / 128, B_ * NH), blk, 0, stream>>>(kqvb, Lr);
  attn_pv    <<<dim3(S_ / 128, B_ * NH), blk, 0, stream>>>(kqvb, vtg, Lr, attnb);

  gemm_bf16<0><<<dim3(HID / 128, M_ / 128), blk, 0, stream>>>(
      attnb, w2t, ff_b, out, M_, HID, HID);
}